// Round 1
// baseline (4289.234 us; speedup 1.0000x reference)
//
#include <hip/hip_runtime.h>

constexpr int NNODES = 100000;
constexpr int NEDGES = 1600000;
constexpr int K = 128;

__global__ void zero_kernel(float4* __restrict__ p, int n4) {
    int i = blockIdx.x * 256 + threadIdx.x;
    if (i < n4) p[i] = make_float4(0.f, 0.f, 0.f, 0.f);
}

__global__ void deg_kernel(const int* __restrict__ dst, float* __restrict__ deg) {
    int e = blockIdx.x * 256 + threadIdx.x;
    if (e < NEDGES) atomicAdd(&deg[dst[e]], 1.0f);
}

// agg[dst[e]][0:F] += feat[src[e]][0:F]; 32 (or 16) consecutive threads per edge
template<int F>
__global__ void scatter_kernel(const int* __restrict__ src, const int* __restrict__ dst,
                               const float* __restrict__ feat, float* __restrict__ agg) {
    constexpr int G = F / 4;
    unsigned idx = blockIdx.x * 256u + threadIdx.x;
    unsigned e = idx / G;
    unsigned g = idx % G;
    if (e >= (unsigned)NEDGES) return;
    int s = src[e], d = dst[e];
    float4 v = *reinterpret_cast<const float4*>(feat + (size_t)s * F + g * 4);
    float* o = agg + (size_t)d * F + (size_t)g * 4;
    atomicAdd(o + 0, v.x);
    atomicAdd(o + 1, v.y);
    atomicAdd(o + 2, v.z);
    atomicAdd(o + 3, v.w);
}

// C[r][c] = epi( (A1[r]/deg?) @ Wa  (+ A2[r] @ Wb)  + bias + (C[r][c]/deg)? )
// K = 128 fixed. Tile: 64 rows x NOUT cols per 256-thread block.
template<int NOUT, bool TWO, bool RELU, bool DIVA1, bool ADDC, bool BIAS>
__global__ __launch_bounds__(256, 2) void gemm_kernel(
    const float* __restrict__ A1, const float* __restrict__ Wa,
    const float* __restrict__ A2, const float* __restrict__ Wb,
    const float* __restrict__ bias, const float* __restrict__ deg,
    float* __restrict__ C, int M)
{
    constexpr int TM  = 64;
    constexpr int KC  = 32;
    constexpr int CT  = NOUT / 4;     // threads along cols (32 or 16)
    constexpr int RT  = 256 / CT;     // threads along rows (8 or 16)
    constexpr int RPT = TM / RT;      // rows per thread (8 or 4)

    __shared__ float As[KC][TM + 4];  // transposed A chunk, stride 68 (16B-aligned rows)
    __shared__ float Ws[KC][NOUT];

    const int tid  = threadIdx.x;
    const int row0 = blockIdx.x * TM;

    // loader mapping: each thread loads 8 consecutive k of one row
    const int arow   = tid >> 2;          // 0..63
    const int kq     = (tid & 3) * 8;     // 0,8,16,24
    const int lrow   = row0 + arow;
    const bool lvalid = lrow < M;

    float lscale1 = 1.0f;
    if (DIVA1 && lvalid) lscale1 = 1.0f / fmaxf(deg[lrow], 1.0f);

    const int tc = tid % CT;
    const int tr = tid / CT;

    float acc[RPT][4];
    #pragma unroll
    for (int i = 0; i < RPT; ++i)
        #pragma unroll
        for (int j = 0; j < 4; ++j) acc[i][j] = 0.f;

    #pragma unroll
    for (int mm = 0; mm < (TWO ? 2 : 1); ++mm) {
        const float* __restrict__ A = mm ? A2 : A1;
        const float* __restrict__ W = mm ? Wb : Wa;
        const float s = (mm == 0 && DIVA1) ? lscale1 : 1.0f;
        for (int kk = 0; kk < K; kk += KC) {
            float va[8];
            if (lvalid) {
                const float* ap = A + (size_t)lrow * K + kk + kq;
                float4 v0 = *reinterpret_cast<const float4*>(ap);
                float4 v1 = *reinterpret_cast<const float4*>(ap + 4);
                va[0] = v0.x; va[1] = v0.y; va[2] = v0.z; va[3] = v0.w;
                va[4] = v1.x; va[5] = v1.y; va[6] = v1.z; va[7] = v1.w;
            } else {
                #pragma unroll
                for (int j = 0; j < 8; ++j) va[j] = 0.f;
            }
            #pragma unroll
            for (int j = 0; j < 8; ++j) As[kq + j][arow] = va[j] * s;

            // W chunk is 32 full rows -> contiguous 32*NOUT floats
            constexpr int WQ = KC * NOUT / 4 / 256;   // 4 (NOUT=128) or 2 (NOUT=64)
            const float4* wg = reinterpret_cast<const float4*>(W + kk * NOUT);
            float4* wl = reinterpret_cast<float4*>(&Ws[0][0]);
            #pragma unroll
            for (int q = 0; q < WQ; ++q) wl[tid + q * 256] = wg[tid + q * 256];

            __syncthreads();
            #pragma unroll
            for (int k = 0; k < KC; ++k) {
                float4 w = *reinterpret_cast<const float4*>(&Ws[k][tc * 4]);
                float a[RPT];
                #pragma unroll
                for (int q = 0; q < RPT; q += 4) {
                    float4 av = *reinterpret_cast<const float4*>(&As[k][tr * RPT + q]);
                    a[q] = av.x; a[q + 1] = av.y; a[q + 2] = av.z; a[q + 3] = av.w;
                }
                #pragma unroll
                for (int i = 0; i < RPT; ++i) {
                    acc[i][0] = fmaf(a[i], w.x, acc[i][0]);
                    acc[i][1] = fmaf(a[i], w.y, acc[i][1]);
                    acc[i][2] = fmaf(a[i], w.z, acc[i][2]);
                    acc[i][3] = fmaf(a[i], w.w, acc[i][3]);
                }
            }
            __syncthreads();
        }
    }

    float4 bv = make_float4(0.f, 0.f, 0.f, 0.f);
    if (BIAS) bv = *reinterpret_cast<const float4*>(bias + tc * 4);
    #pragma unroll
    for (int i = 0; i < RPT; ++i) {
        int r = row0 + tr * RPT + i;
        if (r >= M) continue;
        float4 o;
        o.x = acc[i][0] + bv.x; o.y = acc[i][1] + bv.y;
        o.z = acc[i][2] + bv.z; o.w = acc[i][3] + bv.w;
        float4* cp = reinterpret_cast<float4*>(C + (size_t)r * NOUT + tc * 4);
        if (ADDC) {
            float rd = 1.0f / fmaxf(deg[r], 1.0f);
            float4 ci = *cp;
            o.x += ci.x * rd; o.y += ci.y * rd;
            o.z += ci.z * rd; o.w += ci.w * rd;
        }
        if (RELU) {
            o.x = fmaxf(o.x, 0.f); o.y = fmaxf(o.y, 0.f);
            o.z = fmaxf(o.z, 0.f); o.w = fmaxf(o.w, 0.f);
        }
        *cp = o;
    }
}

extern "C" void kernel_launch(void* const* d_in, const int* in_sizes, int n_in,
                              void* d_out, int out_size, void* d_ws, size_t ws_size,
                              hipStream_t stream)
{
    const float* x   = (const float*)d_in[0];
    const int*   ei  = (const int*)d_in[1];
    const float* W1l = (const float*)d_in[2];
    const float* W1r = (const float*)d_in[3];
    const float* b1  = (const float*)d_in[4];
    const float* W2l = (const float*)d_in[5];
    const float* W2r = (const float*)d_in[6];
    const float* b2  = (const float*)d_in[7];
    const int* src = ei;
    const int* dst = ei + NEDGES;

    char* ws = (char*)d_ws;
    float* deg = (float*)ws;                                   // N floats
    const size_t off_agg1 = 400384;                            // 16B-aligned
    float* agg1 = (float*)(ws + off_agg1);                     // N*128 floats
    float* p    = agg1;                                        // reuse after layer 1
    const size_t off_h = off_agg1 + (size_t)NNODES * 128 * 4;  // 51,600,384
    float* h    = (float*)(ws + off_h);                        // N*128 floats
    float* out  = (float*)d_out;                               // N*64, doubles as agg2

    // zero deg + agg1 region
    {
        int n4 = (int)(off_h / 16);
        zero_kernel<<<(n4 + 255) / 256, 256, 0, stream>>>((float4*)ws, n4);
    }
    deg_kernel<<<(NEDGES + 255) / 256, 256, 0, stream>>>(dst, deg);

    // layer 1 aggregate: agg1[dst] += x[src]
    scatter_kernel<128><<<(NEDGES * 32) / 256, 256, 0, stream>>>(src, dst, x, agg1);

    // h = relu(agg1/deg @ W1_l + x @ W1_r + b1)
    gemm_kernel<128, true, true, true, false, true>
        <<<(NNODES + 63) / 64, 256, 0, stream>>>(agg1, W1l, x, W1r, b1, deg, h, NNODES);

    // p = h @ W2_l   (aggregate commutes with linear map: mean(h)@W = mean(h@W))
    gemm_kernel<64, false, false, false, false, false>
        <<<(NNODES + 63) / 64, 256, 0, stream>>>(h, W2l, nullptr, nullptr, nullptr, deg, p, NNODES);

    // zero d_out, then agg2(out)[dst] += p[src]
    {
        int n4 = NNODES * 64 / 4;
        zero_kernel<<<(n4 + 255) / 256, 256, 0, stream>>>((float4*)out, n4);
    }
    scatter_kernel<64><<<(NEDGES * 16) / 256, 256, 0, stream>>>(src, dst, p, out);

    // out = out/deg + h @ W2_r + b2
    gemm_kernel<64, false, false, false, true, true>
        <<<(NNODES + 63) / 64, 256, 0, stream>>>(h, W2r, nullptr, nullptr, b2, deg, out, NNODES);
}

// Round 2
// 542.353 us; speedup vs baseline: 7.9086x; 7.9086x over previous
//
#include <hip/hip_runtime.h>

constexpr int NNODES = 100000;
constexpr int NEDGES = 1600000;
constexpr int K = 128;
constexpr int NB1 = (NNODES + 255) / 256;   // 391 scan blocks

__global__ void zero_int_kernel(int* __restrict__ p, int n) {
    int i = blockIdx.x * 256 + threadIdx.x;
    if (i < n) p[i] = 0;
}

__global__ void hist_kernel(const int* __restrict__ dst, int* __restrict__ deg) {
    int e = blockIdx.x * 256 + threadIdx.x;
    if (e < NEDGES) atomicAdd(&deg[dst[e]], 1);
}

// exclusive scan, stage 1: per-256-block scan + block sums
__global__ void scan1_kernel(const int* __restrict__ deg, int* __restrict__ row_start,
                             int* __restrict__ blocksum) {
    __shared__ int tmp[256];
    int i = blockIdx.x * 256 + threadIdx.x;
    int v = (i < NNODES) ? deg[i] : 0;
    tmp[threadIdx.x] = v;
    __syncthreads();
    #pragma unroll
    for (int off = 1; off < 256; off <<= 1) {
        int t = (threadIdx.x >= off) ? tmp[threadIdx.x - off] : 0;
        __syncthreads();
        tmp[threadIdx.x] += t;
        __syncthreads();
    }
    if (i < NNODES) row_start[i] = tmp[threadIdx.x] - v;   // exclusive
    if (threadIdx.x == 255) blocksum[blockIdx.x] = tmp[255];
}

// stage 2: single block scans the 391 block sums (exclusive)
__global__ void scan2_kernel(int* __restrict__ blocksum, int* __restrict__ blockoff) {
    __shared__ int tmp[512];
    int t = threadIdx.x;
    int v = (t < NB1) ? blocksum[t] : 0;
    tmp[t] = v;
    __syncthreads();
    #pragma unroll
    for (int off = 1; off < 512; off <<= 1) {
        int u = (t >= off) ? tmp[t - off] : 0;
        __syncthreads();
        tmp[t] += u;
        __syncthreads();
    }
    if (t < NB1) blockoff[t] = tmp[t] - v;
}

// stage 3: add block offsets, init cursor = row_start
__global__ void scan3_kernel(int* __restrict__ row_start, const int* __restrict__ blockoff,
                             int* __restrict__ cursor) {
    int i = blockIdx.x * 256 + threadIdx.x;
    if (i < NNODES) {
        int rs = row_start[i] + blockoff[blockIdx.x];
        row_start[i] = rs;
        cursor[i] = rs;
    }
}

// fill CSR adjacency: csr_src[pos] = src[e]; cursor ends up = row_end
__global__ void fill_kernel(const int* __restrict__ src, const int* __restrict__ dst,
                            int* __restrict__ cursor, int* __restrict__ csr_src) {
    int e = blockIdx.x * 256 + threadIdx.x;
    if (e < NEDGES) {
        int pos = atomicAdd(&cursor[dst[e]], 1);
        csr_src[pos] = src[e];
    }
}

// out[n] = mean over incoming neighbors of feat[src] (F floats per row)
template<int F>
__global__ void gather_mean_kernel(const int* __restrict__ row_start,
                                   const int* __restrict__ row_end,
                                   const int* __restrict__ csr_src,
                                   const float* __restrict__ feat,
                                   float* __restrict__ out) {
    constexpr int G = F / 4;        // lanes per node (32 or 16)
    constexpr int NPB = 256 / G;    // nodes per block (8 or 16)
    int node = blockIdx.x * NPB + threadIdx.x / G;
    int lane = threadIdx.x % G;
    if (node >= NNODES) return;
    int beg = row_start[node];
    int end = row_end[node];
    float4 a0 = make_float4(0.f, 0.f, 0.f, 0.f);
    float4 a1 = make_float4(0.f, 0.f, 0.f, 0.f);
    int j = beg;
    for (; j + 1 < end; j += 2) {
        int s0 = csr_src[j];
        int s1 = csr_src[j + 1];
        float4 v0 = *reinterpret_cast<const float4*>(feat + (size_t)s0 * F + lane * 4);
        float4 v1 = *reinterpret_cast<const float4*>(feat + (size_t)s1 * F + lane * 4);
        a0.x += v0.x; a0.y += v0.y; a0.z += v0.z; a0.w += v0.w;
        a1.x += v1.x; a1.y += v1.y; a1.z += v1.z; a1.w += v1.w;
    }
    if (j < end) {
        int s0 = csr_src[j];
        float4 v0 = *reinterpret_cast<const float4*>(feat + (size_t)s0 * F + lane * 4);
        a0.x += v0.x; a0.y += v0.y; a0.z += v0.z; a0.w += v0.w;
    }
    float inv = 1.0f / fmaxf((float)(end - beg), 1.0f);
    float4 o;
    o.x = (a0.x + a1.x) * inv; o.y = (a0.y + a1.y) * inv;
    o.z = (a0.z + a1.z) * inv; o.w = (a0.w + a1.w) * inv;
    *reinterpret_cast<float4*>(out + (size_t)node * F + lane * 4) = o;
}

// C[r] = epi( A1[r]@Wa (+ A2[r]@Wb) + bias (+ C[r]) ); K=128 fixed.
template<int NOUT, bool TWO, bool RELU, bool ADDC, bool BIAS>
__global__ __launch_bounds__(256, 2) void gemm_kernel(
    const float* __restrict__ A1, const float* __restrict__ Wa,
    const float* __restrict__ A2, const float* __restrict__ Wb,
    const float* __restrict__ bias,
    float* __restrict__ C, int M)
{
    constexpr int TM  = 64;
    constexpr int KC  = 32;
    constexpr int CT  = NOUT / 4;     // threads along cols (32 or 16)
    constexpr int RT  = 256 / CT;     // threads along rows (8 or 16)
    constexpr int RPT = TM / RT;      // rows per thread (8 or 4)

    __shared__ float As[KC][TM + 4];
    __shared__ float Ws[KC][NOUT];

    const int tid  = threadIdx.x;
    const int row0 = blockIdx.x * TM;

    const int arow   = tid >> 2;
    const int kq     = (tid & 3) * 8;
    const int lrow   = row0 + arow;
    const bool lvalid = lrow < M;

    const int tc = tid % CT;
    const int tr = tid / CT;

    float acc[RPT][4];
    #pragma unroll
    for (int i = 0; i < RPT; ++i)
        #pragma unroll
        for (int j = 0; j < 4; ++j) acc[i][j] = 0.f;

    #pragma unroll
    for (int mm = 0; mm < (TWO ? 2 : 1); ++mm) {
        const float* __restrict__ A = mm ? A2 : A1;
        const float* __restrict__ W = mm ? Wb : Wa;
        for (int kk = 0; kk < K; kk += KC) {
            float va[8];
            if (lvalid) {
                const float* ap = A + (size_t)lrow * K + kk + kq;
                float4 v0 = *reinterpret_cast<const float4*>(ap);
                float4 v1 = *reinterpret_cast<const float4*>(ap + 4);
                va[0] = v0.x; va[1] = v0.y; va[2] = v0.z; va[3] = v0.w;
                va[4] = v1.x; va[5] = v1.y; va[6] = v1.z; va[7] = v1.w;
            } else {
                #pragma unroll
                for (int j = 0; j < 8; ++j) va[j] = 0.f;
            }
            #pragma unroll
            for (int j = 0; j < 8; ++j) As[kq + j][arow] = va[j];

            constexpr int WQ = KC * NOUT / 4 / 256;
            const float4* wg = reinterpret_cast<const float4*>(W + kk * NOUT);
            float4* wl = reinterpret_cast<float4*>(&Ws[0][0]);
            #pragma unroll
            for (int q = 0; q < WQ; ++q) wl[tid + q * 256] = wg[tid + q * 256];

            __syncthreads();
            #pragma unroll
            for (int k = 0; k < KC; ++k) {
                float4 w = *reinterpret_cast<const float4*>(&Ws[k][tc * 4]);
                float a[RPT];
                #pragma unroll
                for (int q = 0; q < RPT; q += 4) {
                    float4 av = *reinterpret_cast<const float4*>(&As[k][tr * RPT + q]);
                    a[q] = av.x; a[q + 1] = av.y; a[q + 2] = av.z; a[q + 3] = av.w;
                }
                #pragma unroll
                for (int i = 0; i < RPT; ++i) {
                    acc[i][0] = fmaf(a[i], w.x, acc[i][0]);
                    acc[i][1] = fmaf(a[i], w.y, acc[i][1]);
                    acc[i][2] = fmaf(a[i], w.z, acc[i][2]);
                    acc[i][3] = fmaf(a[i], w.w, acc[i][3]);
                }
            }
            __syncthreads();
        }
    }

    float4 bv = make_float4(0.f, 0.f, 0.f, 0.f);
    if (BIAS) bv = *reinterpret_cast<const float4*>(bias + tc * 4);
    #pragma unroll
    for (int i = 0; i < RPT; ++i) {
        int r = row0 + tr * RPT + i;
        if (r >= M) continue;
        float4 o;
        o.x = acc[i][0] + bv.x; o.y = acc[i][1] + bv.y;
        o.z = acc[i][2] + bv.z; o.w = acc[i][3] + bv.w;
        float4* cp = reinterpret_cast<float4*>(C + (size_t)r * NOUT + tc * 4);
        if (ADDC) {
            float4 ci = *cp;
            o.x += ci.x; o.y += ci.y; o.z += ci.z; o.w += ci.w;
        }
        if (RELU) {
            o.x = fmaxf(o.x, 0.f); o.y = fmaxf(o.y, 0.f);
            o.z = fmaxf(o.z, 0.f); o.w = fmaxf(o.w, 0.f);
        }
        *cp = o;
    }
}

extern "C" void kernel_launch(void* const* d_in, const int* in_sizes, int n_in,
                              void* d_out, int out_size, void* d_ws, size_t ws_size,
                              hipStream_t stream)
{
    const float* x   = (const float*)d_in[0];
    const int*   ei  = (const int*)d_in[1];
    const float* W1l = (const float*)d_in[2];
    const float* W1r = (const float*)d_in[3];
    const float* b1  = (const float*)d_in[4];
    const float* W2l = (const float*)d_in[5];
    const float* W2r = (const float*)d_in[6];
    const float* b2  = (const float*)d_in[7];
    const int* src = ei;
    const int* dst = ei + NEDGES;

    char* ws = (char*)d_ws;
    // layout (bytes, all 128-aligned)
    int*   deg_i     = (int*)(ws + 0);             // 400,000 B
    int*   row_start = (int*)(ws + 400128);        // 400,000 B
    int*   cursor    = (int*)(ws + 800256);        // 400,000 B (becomes row_end)
    int*   blocksum  = (int*)(ws + 1200384);       // 1,564 B
    int*   blockoff  = (int*)(ws + 1202048);       // 1,564 B
    int*   csr_src   = (int*)(ws + 1203712);       // 6,400,000 B
    float* agg1      = (float*)(ws + 7603712);     // 51,200,000 B
    float* p         = agg1;                       // reuse after layer 1
    float* h         = (float*)(ws + 58803712);    // 51,200,000 B
    float* out       = (float*)d_out;              // N*64, doubles as agg2

    // ---- build CSR (shared by both layers) ----
    zero_int_kernel<<<(NNODES + 255) / 256, 256, 0, stream>>>(deg_i, NNODES);
    hist_kernel<<<(NEDGES + 255) / 256, 256, 0, stream>>>(dst, deg_i);
    scan1_kernel<<<NB1, 256, 0, stream>>>(deg_i, row_start, blocksum);
    scan2_kernel<<<1, 512, 0, stream>>>(blocksum, blockoff);
    scan3_kernel<<<NB1, 256, 0, stream>>>(row_start, blockoff, cursor);
    fill_kernel<<<(NEDGES + 255) / 256, 256, 0, stream>>>(src, dst, cursor, csr_src);
    // cursor now holds row_end

    // ---- layer 1 ----
    gather_mean_kernel<128><<<(NNODES + 7) / 8, 256, 0, stream>>>(
        row_start, cursor, csr_src, x, agg1);
    gemm_kernel<128, true, true, false, true>
        <<<(NNODES + 63) / 64, 256, 0, stream>>>(agg1, W1l, x, W1r, b1, h, NNODES);

    // ---- layer 2 (aggregate commutes with linear map) ----
    gemm_kernel<64, false, false, false, false>
        <<<(NNODES + 63) / 64, 256, 0, stream>>>(h, W2l, nullptr, nullptr, nullptr, p, NNODES);
    gather_mean_kernel<64><<<(NNODES + 15) / 16, 256, 0, stream>>>(
        row_start, cursor, csr_src, p, out);
    gemm_kernel<64, false, false, true, true>
        <<<(NNODES + 63) / 64, 256, 0, stream>>>(h, W2r, nullptr, nullptr, b2, out, NNODES);
}